// Round 7
// baseline (378.640 us; speedup 1.0000x reference)
//
#include <hip/hip_runtime.h>
#include <hip/hip_bf16.h>
#include <math.h>

#define NN 8192
#define HD 128
#define NB 2
#define EPSF 1e-6f
#define BM 16
#define BK 128
#define NSTEP (NN / BK)   // 64

typedef __attribute__((ext_vector_type(8))) __bf16 bf16x8;
typedef __attribute__((ext_vector_type(4))) float f32x4;

// ---------------- Kernel 1: norm = rsqrt(sum|adj_row| + eps) -----------------
__global__ __launch_bounds__(256) void k_degree(const float* __restrict__ adj,
                                                float* __restrict__ norm) {
    const int row  = blockIdx.x * 4 + (threadIdx.x >> 6);
    const int lane = threadIdx.x & 63;
    const float4* p = (const float4*)(adj + (size_t)row * NN);
    float s = 0.f;
#pragma unroll
    for (int i = 0; i < 32; ++i) {
        float4 v = p[(size_t)i * 64 + lane];
        s += fabsf(v.x) + fabsf(v.y) + fabsf(v.z) + fabsf(v.w);
    }
#pragma unroll
    for (int off = 32; off > 0; off >>= 1) s += __shfl_down(s, off);
    if (lane == 0) norm[row] = rsqrtf(s + EPSF);
}

// ------- Kernel 2: snT[b][h][n] = bf16( (x@W)[b][n][h] * norm[b][n] ) --------
__global__ __launch_bounds__(256) void k_support(const float* __restrict__ x,
                                                 const float* __restrict__ W,
                                                 const float* __restrict__ norm,
                                                 __hip_bfloat16* __restrict__ snT) {
    const int b  = blockIdx.x >> 9;
    const int n0 = (blockIdx.x & 511) * 16;
    __shared__ float xs[16][132];
    const int t = threadIdx.x;
    {
        const int r = t >> 4, c0 = (t & 15) * 8;
        const float* src = x + ((size_t)(b * NN + n0 + r)) * HD + c0;
        *(float4*)&xs[r][c0]     = *(const float4*)src;
        *(float4*)&xs[r][c0 + 4] = *(const float4*)(src + 4);
    }
    __syncthreads();
    const int nl = t & 15;
    const int h0 = (t >> 4) * 8;
    float s[8] = {0.f,0.f,0.f,0.f,0.f,0.f,0.f,0.f};
#pragma unroll 4
    for (int k = 0; k < HD; ++k) {
        const float xv = xs[nl][k];
        const float* wr = W + k * HD + h0;
        float4 wa = *(const float4*)wr;
        float4 wb = *(const float4*)(wr + 4);
        s[0] += xv * wa.x; s[1] += xv * wa.y; s[2] += xv * wa.z; s[3] += xv * wa.w;
        s[4] += xv * wb.x; s[5] += xv * wb.y; s[6] += xv * wb.z; s[7] += xv * wb.w;
    }
    const float nv = norm[b * NN + n0 + nl];
#pragma unroll
    for (int hb = 0; hb < 8; ++hb)
        snT[((size_t)b * HD + h0 + hb) * NN + n0 + nl] = __float2bfloat16(s[hb] * nv);
}

__device__ __forceinline__ bf16x8 cvt8(float4 a, float4 b) {
    bf16x8 r;
    r[0] = (__bf16)a.x; r[1] = (__bf16)a.y; r[2] = (__bf16)a.z; r[3] = (__bf16)a.w;
    r[4] = (__bf16)b.x; r[5] = (__bf16)b.y; r[6] = (__bf16)b.z; r[7] = (__bf16)b.w;
    return r;
}

// async global->LDS, 16 B per lane (dest = wave-uniform base + lane*16)
__device__ __forceinline__ void gload_lds16(const float* g, void* l) {
    __builtin_amdgcn_global_load_lds(
        (const __attribute__((address_space(1))) void*)g,
        (__attribute__((address_space(3))) void*)l, 16, 0, 0);
}

// ---- Kernel 3: out = elu( norm_m * (adj[b] @ snT[b]^T) + bias ) -------------
// Barrier-paced global_load_lds pipeline. BM=16 / BK=128 -> 8 KB tile, 16 KB
// LDS double buffer, VGPR ~80 under the (256,4) 128-cap: 1024 blocks = 4
// resident/CU. The barrier's vmcnt(0) drain is per-block; 4 staggered blocks
// keep the CU's HBM queue fed through any one block's drain window (the
// round-6 lesson: blocks/CU, not tile size, is the drain-hiding lever).
// XOR swizzle (16B-granule ^ row&7) applied on the global source AND the LDS
// read (both-sides involution): staging coalesced, ds_read_b128 conflict-free.
__global__ __launch_bounds__(256, 4) void k_gemm7(const float* __restrict__ adj,
                                                  const __hip_bfloat16* __restrict__ snT,
                                                  const float* __restrict__ norm,
                                                  const float* __restrict__ bias,
                                                  float* __restrict__ out) {
    const int b    = blockIdx.y;
    const int m0   = blockIdx.x * BM;
    const int w    = threadIdx.x >> 6;     // wave id = h-slice owner (h0 = w*32)
    const int lane = threadIdx.x & 63;
    const int fr   = lane & 15;
    const int g    = lane >> 4;

    const float* adjB = adj + (size_t)b * NN * NN;
    const __hip_bfloat16* snB = snT + (size_t)b * HD * NN;

    __shared__ __align__(16) char Abuf[2][BM * BK * 4];   // 2 x 8 KB

    // staging: wave w, call c covers 16B-granules fg = (w*2+c)*64 + lane;
    // row = fg>>5 (32 granules/row), in-row slot = fg&31, source slot XOR'd.
    const float* sptr[2];
#pragma unroll
    for (int c = 0; c < 2; ++c) {
        const int fg   = (w * 2 + c) * 64 + lane;
        const int row  = fg >> 5;
        const int gs   = (fg & 31) ^ (row & 7);
        sptr[c] = adjB + (size_t)(m0 + row) * NN + gs * 4;
    }

    // B base pointers (per h-tile); fragment = bf16x8 at k = s*BK + ks*32 + g*8
    const __hip_bfloat16* bp0 = snB + (size_t)(w * 32 + fr) * NN + g * 8;
    const __hip_bfloat16* bp1 = bp0 + (size_t)16 * NN;

    f32x4 acc[2] = {};   // [h-tile]
    const int xr = fr & 7;

    // ---- prologue: stage step 0 into buf 0 ----
#pragma unroll
    for (int c = 0; c < 2; ++c)
        gload_lds16(sptr[c], &Abuf[0][(w * 2 + c) * 1024]);

#pragma unroll 1
    for (int s = 0; s < NSTEP; ++s) {
        __syncthreads();               // buf[s&1] staged; prev-step reads done
        const char* lb = Abuf[s & 1];

        // B fragments for this step (issued before staging: their counted
        // vmcnt wait never drains the stage queue)
        bf16x8 Bf[2][4];
#pragma unroll
        for (int ks = 0; ks < 4; ++ks) {
            Bf[0][ks] = *(const bf16x8*)(bp0 + s * BK + ks * 32);
            Bf[1][ks] = *(const bf16x8*)(bp1 + s * BK + ks * 32);
        }

        // stage next adj tile into the other buffer
        if (s + 1 < NSTEP) {
            char* nb = Abuf[(s + 1) & 1];
#pragma unroll
            for (int c = 0; c < 2; ++c)
                gload_lds16(sptr[c] + (s + 1) * BK, &nb[(w * 2 + c) * 1024]);
        }

        // compute from buf[s&1]: row fr (512 B), 16B-slot = ks*8 + ((g*2+j)^xr)
        const char* rbase = lb + fr * 512;
#pragma unroll
        for (int ks = 0; ks < 4; ++ks) {
            float4 fa = *(const float4*)(rbase + ((ks * 8 + ((g * 2 + 0) ^ xr)) << 4));
            float4 fb = *(const float4*)(rbase + ((ks * 8 + ((g * 2 + 1) ^ xr)) << 4));
            bf16x8 af = cvt8(fa, fb);
            acc[0] = __builtin_amdgcn_mfma_f32_16x16x32_bf16(af, Bf[0][ks], acc[0], 0, 0, 0);
            acc[1] = __builtin_amdgcn_mfma_f32_16x16x32_bf16(af, Bf[1][ks], acc[1], 0, 0, 0);
        }
    }

    // ---- fused epilogue: *norm_m + bias, elu ----
    const float* normB = norm + b * NN + m0;
    float* outB = out + ((size_t)b * NN + m0) * HD;
#pragma unroll
    for (int ht = 0; ht < 2; ++ht) {
        const int h  = w * 32 + ht * 16 + fr;
        const float bv = bias[h];
#pragma unroll
        for (int j = 0; j < 4; ++j) {
            const int r = g * 4 + j;
            float v = acc[ht][j] * normB[r] + bv;
            v = v > 0.f ? v : expm1f(v);
            outB[(size_t)r * HD + h] = v;
        }
    }
}

extern "C" void kernel_launch(void* const* d_in, const int* in_sizes, int n_in,
                              void* d_out, int out_size, void* d_ws, size_t ws_size,
                              hipStream_t stream) {
    (void)in_sizes; (void)n_in; (void)out_size; (void)ws_size;
    const float* x    = (const float*)d_in[0];
    const float* adj  = (const float*)d_in[1];
    const float* W    = (const float*)d_in[2];
    const float* bias = (const float*)d_in[3];
    float* out = (float*)d_out;

    float* norm = (float*)d_ws;                                    // 16384 f32
    __hip_bfloat16* snT = (__hip_bfloat16*)((char*)d_ws + 65536);  // 2x128x8192 bf16 (4 MB)

    k_degree <<<dim3(NB * NN / 4),  dim3(256), 0, stream>>>(adj, norm);
    k_support<<<dim3(NB * NN / 16), dim3(256), 0, stream>>>(x, W, norm, snT);
    k_gemm7  <<<dim3(NN / BM, NB),  dim3(256), 0, stream>>>(adj, snT, norm, bias, out);
}

// Round 8
// 280.167 us; speedup vs baseline: 1.3515x; 1.3515x over previous
//
#include <hip/hip_runtime.h>
#include <hip/hip_bf16.h>
#include <math.h>

#define NN 8192
#define HD 128
#define NB 2
#define EPSF 1e-6f
#define BM 32
#define BK 128
#define NSTEP (NN / BK)   // 64

typedef __attribute__((ext_vector_type(8))) __bf16 bf16x8;
typedef __attribute__((ext_vector_type(4))) float f32x4;

// ---------------- Kernel 1: norm = rsqrt(sum|adj_row| + eps) -----------------
__global__ __launch_bounds__(256) void k_degree(const float* __restrict__ adj,
                                                float* __restrict__ norm) {
    const int row  = blockIdx.x * 4 + (threadIdx.x >> 6);
    const int lane = threadIdx.x & 63;
    const float4* p = (const float4*)(adj + (size_t)row * NN);
    float s = 0.f;
#pragma unroll
    for (int i = 0; i < 32; ++i) {
        float4 v = p[(size_t)i * 64 + lane];
        s += fabsf(v.x) + fabsf(v.y) + fabsf(v.z) + fabsf(v.w);
    }
#pragma unroll
    for (int off = 32; off > 0; off >>= 1) s += __shfl_down(s, off);
    if (lane == 0) norm[row] = rsqrtf(s + EPSF);
}

// ------- Kernel 2: snT[b][h][n] = bf16( (x@W)[b][n][h] * norm[b][n] ) --------
__global__ __launch_bounds__(256) void k_support(const float* __restrict__ x,
                                                 const float* __restrict__ W,
                                                 const float* __restrict__ norm,
                                                 __hip_bfloat16* __restrict__ snT) {
    const int b  = blockIdx.x >> 9;
    const int n0 = (blockIdx.x & 511) * 16;
    __shared__ float xs[16][132];
    const int t = threadIdx.x;
    {
        const int r = t >> 4, c0 = (t & 15) * 8;
        const float* src = x + ((size_t)(b * NN + n0 + r)) * HD + c0;
        *(float4*)&xs[r][c0]     = *(const float4*)src;
        *(float4*)&xs[r][c0 + 4] = *(const float4*)(src + 4);
    }
    __syncthreads();
    const int nl = t & 15;
    const int h0 = (t >> 4) * 8;
    float s[8] = {0.f,0.f,0.f,0.f,0.f,0.f,0.f,0.f};
#pragma unroll 4
    for (int k = 0; k < HD; ++k) {
        const float xv = xs[nl][k];
        const float* wr = W + k * HD + h0;
        float4 wa = *(const float4*)wr;
        float4 wb = *(const float4*)(wr + 4);
        s[0] += xv * wa.x; s[1] += xv * wa.y; s[2] += xv * wa.z; s[3] += xv * wa.w;
        s[4] += xv * wb.x; s[5] += xv * wb.y; s[6] += xv * wb.z; s[7] += xv * wb.w;
    }
    const float nv = norm[b * NN + n0 + nl];
#pragma unroll
    for (int hb = 0; hb < 8; ++hb)
        snT[((size_t)b * HD + h0 + hb) * NN + n0 + nl] = __float2bfloat16(s[hb] * nv);
}

__device__ __forceinline__ bf16x8 cvt8(float4 a, float4 b) {
    bf16x8 r;
    r[0] = (__bf16)a.x; r[1] = (__bf16)a.y; r[2] = (__bf16)a.z; r[3] = (__bf16)a.w;
    r[4] = (__bf16)b.x; r[5] = (__bf16)b.y; r[6] = (__bf16)b.z; r[7] = (__bf16)b.w;
    return r;
}

// async global->LDS, 16 B per lane (dest = wave-uniform base + lane*16)
__device__ __forceinline__ void gload_lds16(const float* g, void* l) {
    __builtin_amdgcn_global_load_lds(
        (const __attribute__((address_space(1))) void*)g,
        (__attribute__((address_space(3))) void*)l, 16, 0, 0);
}

// ---- Kernel 3: out = elu( norm_m * (adj[b] @ snT[b]^T) + bias ) -------------
// R5 structure (best known, 175us) with two minimal changes:
//  * __launch_bounds__(256,4): cap VGPR at 128 so occupancy is 4-5 blocks/CU
//    (R5's (256,2) let VGPR float -> 2 blocks/CU); staggered blocks cover each
//    other's barrier-drain windows and B-load latency.
//  * XCD-bijective swizzle of blockIdx.x (256 = 8 XCD x 32): each XCD owns a
//    contiguous m-chunk and all blocks walk K in lockstep order -> snT slices
//    and the L3-resident adj tail get time-correlated reuse per XCD L2.
// Everything else byte-identical to the verified R5 kernel.
__global__ __launch_bounds__(256, 4) void k_gemm8(const float* __restrict__ adj,
                                                  const __hip_bfloat16* __restrict__ snT,
                                                  const float* __restrict__ norm,
                                                  const float* __restrict__ bias,
                                                  float* __restrict__ out) {
    const int b    = blockIdx.y;
    // XCD-aware bijective swizzle: block i lands on XCD i%8; give XCD j the
    // contiguous m-chunk [j*32, (j+1)*32).  grid.x = 256 divides 8 exactly.
    const int swz  = (blockIdx.x & 7) * 32 + (blockIdx.x >> 3);
    const int m0   = swz * BM;
    const int w    = threadIdx.x >> 6;     // wave id = h-slice owner (h0 = w*32)
    const int lane = threadIdx.x & 63;
    const int fr   = lane & 15;
    const int g    = lane >> 4;

    const float* adjB = adj + (size_t)b * NN * NN;
    const __hip_bfloat16* snB = snT + (size_t)b * HD * NN;

    __shared__ __align__(16) char Abuf[2][BM * BK * 4];   // 2 x 16 KB

    // staging: wave w, call c covers 16B-granules fg = (w*4+c)*64 + lane;
    // row = fg>>5 (32 granules/row), in-row slot = fg&31, source slot XOR'd
    // with row&7 (involution; stays within the 512B row -> coalesced).
    const float* sptr[4];
#pragma unroll
    for (int c = 0; c < 4; ++c) {
        const int fg   = (w * 4 + c) * 64 + lane;
        const int row  = fg >> 5;
        const int gsrc = (fg & 31) ^ (row & 7);
        sptr[c] = adjB + (size_t)(m0 + row) * NN + gsrc * 4;
    }

    // B base pointers (per h-tile); fragment = bf16x8 at k = s*BK + ks*32 + g*8
    const __hip_bfloat16* bp0 = snB + (size_t)(w * 32 + fr) * NN + g * 8;
    const __hip_bfloat16* bp1 = bp0 + (size_t)16 * NN;

    f32x4 acc[2][2] = {};   // [m-tile][h-tile]
    const int xr = fr & 7;

    // ---- prologue: stage step 0 into buf 0 ----
#pragma unroll
    for (int c = 0; c < 4; ++c)
        gload_lds16(sptr[c], &Abuf[0][(w * 4 + c) * 1024]);

#pragma unroll 1
    for (int s = 0; s < NSTEP; ++s) {
        __syncthreads();               // buf[s&1] staged; prev-step reads done
        const char* lb = Abuf[s & 1];

        // B fragments for this step (issued before staging: their counted
        // vmcnt wait never drains the stage queue)
        bf16x8 Bf[2][4];
#pragma unroll
        for (int ks = 0; ks < 4; ++ks) {
            Bf[0][ks] = *(const bf16x8*)(bp0 + s * BK + ks * 32);
            Bf[1][ks] = *(const bf16x8*)(bp1 + s * BK + ks * 32);
        }

        // stage next adj tile into the other buffer
        if (s + 1 < NSTEP) {
            char* nb = Abuf[(s + 1) & 1];
#pragma unroll
            for (int c = 0; c < 4; ++c)
                gload_lds16(sptr[c] + (s + 1) * BK, &nb[(w * 4 + c) * 1024]);
        }

        // compute from buf[s&1]
#pragma unroll
        for (int mt = 0; mt < 2; ++mt) {
            const char* rbase = lb + (mt * 16 + fr) * 512;
#pragma unroll
            for (int ks = 0; ks < 4; ++ks) {
                float4 fa = *(const float4*)(rbase + ((ks * 8 + ((g * 2 + 0) ^ xr)) << 4));
                float4 fb = *(const float4*)(rbase + ((ks * 8 + ((g * 2 + 1) ^ xr)) << 4));
                bf16x8 af = cvt8(fa, fb);
                acc[mt][0] = __builtin_amdgcn_mfma_f32_16x16x32_bf16(af, Bf[0][ks], acc[mt][0], 0, 0, 0);
                acc[mt][1] = __builtin_amdgcn_mfma_f32_16x16x32_bf16(af, Bf[1][ks], acc[mt][1], 0, 0, 0);
            }
        }
    }

    // ---- fused epilogue: *norm_m + bias, elu ----
    const float* normB = norm + b * NN + m0;
    float* outB = out + ((size_t)b * NN + m0) * HD;
#pragma unroll
    for (int mt = 0; mt < 2; ++mt)
#pragma unroll
        for (int ht = 0; ht < 2; ++ht) {
            const int h  = w * 32 + ht * 16 + fr;
            const float bv = bias[h];
#pragma unroll
            for (int j = 0; j < 4; ++j) {
                const int r = mt * 16 + g * 4 + j;
                float v = acc[mt][ht][j] * normB[r] + bv;
                v = v > 0.f ? v : expm1f(v);
                outB[(size_t)r * HD + h] = v;
            }
        }
}

extern "C" void kernel_launch(void* const* d_in, const int* in_sizes, int n_in,
                              void* d_out, int out_size, void* d_ws, size_t ws_size,
                              hipStream_t stream) {
    (void)in_sizes; (void)n_in; (void)out_size; (void)ws_size;
    const float* x    = (const float*)d_in[0];
    const float* adj  = (const float*)d_in[1];
    const float* W    = (const float*)d_in[2];
    const float* bias = (const float*)d_in[3];
    float* out = (float*)d_out;

    float* norm = (float*)d_ws;                                    // 16384 f32
    __hip_bfloat16* snT = (__hip_bfloat16*)((char*)d_ws + 65536);  // 2x128x8192 bf16 (4 MB)

    k_degree <<<dim3(NB * NN / 4),  dim3(256), 0, stream>>>(adj, norm);
    k_support<<<dim3(NB * NN / 16), dim3(256), 0, stream>>>(x, W, norm, snT);
    k_gemm8  <<<dim3(NN / BM, NB),  dim3(256), 0, stream>>>(adj, snT, norm, bias, out);
}

// Round 9
// 274.615 us; speedup vs baseline: 1.3788x; 1.0202x over previous
//
#include <hip/hip_runtime.h>
#include <hip/hip_bf16.h>
#include <math.h>

#define NN 8192
#define HD 128
#define NB 2
#define EPSF 1e-6f
#define BM 32
#define BK 128
#define NSTEP (NN / BK)   // 64 (even, >= 4)

typedef __attribute__((ext_vector_type(8))) __bf16 bf16x8;
typedef __attribute__((ext_vector_type(4))) float f32x4;

// ---------------- Kernel 1: norm = rsqrt(sum|adj_row| + eps) -----------------
__global__ __launch_bounds__(256) void k_degree(const float* __restrict__ adj,
                                                float* __restrict__ norm) {
    const int row  = blockIdx.x * 4 + (threadIdx.x >> 6);
    const int lane = threadIdx.x & 63;
    const float4* p = (const float4*)(adj + (size_t)row * NN);
    float s = 0.f;
#pragma unroll
    for (int i = 0; i < 32; ++i) {
        float4 v = p[(size_t)i * 64 + lane];
        s += fabsf(v.x) + fabsf(v.y) + fabsf(v.z) + fabsf(v.w);
    }
#pragma unroll
    for (int off = 32; off > 0; off >>= 1) s += __shfl_down(s, off);
    if (lane == 0) norm[row] = rsqrtf(s + EPSF);
}

// ------- Kernel 2: snT[b][h][n] = bf16( (x@W)[b][n][h] * norm[b][n] ) --------
__global__ __launch_bounds__(256) void k_support(const float* __restrict__ x,
                                                 const float* __restrict__ W,
                                                 const float* __restrict__ norm,
                                                 __hip_bfloat16* __restrict__ snT) {
    const int b  = blockIdx.x >> 9;
    const int n0 = (blockIdx.x & 511) * 16;
    __shared__ float xs[16][132];
    const int t = threadIdx.x;
    {
        const int r = t >> 4, c0 = (t & 15) * 8;
        const float* src = x + ((size_t)(b * NN + n0 + r)) * HD + c0;
        *(float4*)&xs[r][c0]     = *(const float4*)src;
        *(float4*)&xs[r][c0 + 4] = *(const float4*)(src + 4);
    }
    __syncthreads();
    const int nl = t & 15;
    const int h0 = (t >> 4) * 8;
    float s[8] = {0.f,0.f,0.f,0.f,0.f,0.f,0.f,0.f};
#pragma unroll 4
    for (int k = 0; k < HD; ++k) {
        const float xv = xs[nl][k];
        const float* wr = W + k * HD + h0;
        float4 wa = *(const float4*)wr;
        float4 wb = *(const float4*)(wr + 4);
        s[0] += xv * wa.x; s[1] += xv * wa.y; s[2] += xv * wa.z; s[3] += xv * wa.w;
        s[4] += xv * wb.x; s[5] += xv * wb.y; s[6] += xv * wb.z; s[7] += xv * wb.w;
    }
    const float nv = norm[b * NN + n0 + nl];
#pragma unroll
    for (int hb = 0; hb < 8; ++hb)
        snT[((size_t)b * HD + h0 + hb) * NN + n0 + nl] = __float2bfloat16(s[hb] * nv);
}

__device__ __forceinline__ bf16x8 cvt8(float4 a, float4 b) {
    bf16x8 r;
    r[0] = (__bf16)a.x; r[1] = (__bf16)a.y; r[2] = (__bf16)a.z; r[3] = (__bf16)a.w;
    r[4] = (__bf16)b.x; r[5] = (__bf16)b.y; r[6] = (__bf16)b.z; r[7] = (__bf16)b.w;
    return r;
}

// async global->LDS, 16 B per lane (dest = wave-uniform base + lane*16)
__device__ __forceinline__ void gload_lds16(const float* g, void* l) {
    __builtin_amdgcn_global_load_lds(
        (const __attribute__((address_space(1))) void*)g,
        (__attribute__((address_space(3))) void*)l, 16, 0, 0);
}

// ---- Kernel 3: out = elu( norm_m * (adj[b] @ snT[b]^T) + bias ) -------------
// Counted-vmcnt pipeline (T3/T4): raw s_barrier + manual s_waitcnt vmcnt(16),
// stage-ahead-2 into 4 LDS buffers, B-loads one step ahead in ping-pong reg
// banks. Per half-iter k: issue B(k+1)[8], stage(k+2)[4], then vmcnt(16) --
// in-order retirement leaves exactly {st(k+1), B(k+1), st(k+2)} = 16 in
// flight and guarantees st(k) landed. Stage transfers stay in flight across a
// full step (~3200 cy at HBM fair share): latency fully hidden, no vmcnt(0)
// drain in the main loop. 4 buffers => overwrite of buf[k%4] (stage(k+4),
// issued after barrier k+1) is 2 barriers after its readers (compute k).
// Tail: last 2 steps peeled with vmcnt(0). Data path identical to R8
// (both-sides XOR swizzle, verified 4 rounds).
__global__ __launch_bounds__(256, 2) void k_gemm9(const float* __restrict__ adj,
                                                  const __hip_bfloat16* __restrict__ snT,
                                                  const float* __restrict__ norm,
                                                  const float* __restrict__ bias,
                                                  float* __restrict__ out) {
    const int b    = blockIdx.y;
    const int swz  = (blockIdx.x & 7) * 32 + (blockIdx.x >> 3);   // XCD-bijective
    const int m0   = swz * BM;
    const int w    = threadIdx.x >> 6;
    const int lane = threadIdx.x & 63;
    const int fr   = lane & 15;
    const int g    = lane >> 4;

    const float* adjB = adj + (size_t)b * NN * NN;
    const __hip_bfloat16* snB = snT + (size_t)b * HD * NN;

    __shared__ __align__(16) char Abuf[4][BM * BK * 4];   // 4 x 16 KB

    // staging: wave w, call c covers 16B-granules fg = (w*4+c)*64 + lane;
    // row = fg>>5, in-row slot = (fg&31) ^ (row&7)  (both-sides involution)
    const float* sptr[4];
#pragma unroll
    for (int c = 0; c < 4; ++c) {
        const int fg   = (w * 4 + c) * 64 + lane;
        const int row  = fg >> 5;
        const int gsrc = (fg & 31) ^ (row & 7);
        sptr[c] = adjB + (size_t)(m0 + row) * NN + gsrc * 4;
    }

    const __hip_bfloat16* bp0 = snB + (size_t)(w * 32 + fr) * NN + g * 8;
    const __hip_bfloat16* bp1 = bp0 + (size_t)16 * NN;

    f32x4 acc[2][2] = {};
    const int xr = fr & 7;
    bf16x8 BfA[2][4], BfB[2][4];   // ping-pong B banks

#define STAGE(idx) do {                                                       \
        char* nb_ = Abuf[(idx) & 3];                                          \
        _Pragma("unroll")                                                     \
        for (int c = 0; c < 4; ++c)                                           \
            gload_lds16(sptr[c] + (idx) * BK, &nb_[(w * 4 + c) * 1024]);      \
    } while (0)
#define LOADB(BX, idx) do {                                                   \
        _Pragma("unroll")                                                     \
        for (int ks = 0; ks < 4; ++ks) {                                      \
            BX[0][ks] = *(const bf16x8*)(bp0 + (idx) * BK + ks * 32);         \
            BX[1][ks] = *(const bf16x8*)(bp1 + (idx) * BK + ks * 32);         \
        }                                                                     \
    } while (0)
#define WAITN(n) asm volatile("s_waitcnt vmcnt(" #n ")" ::: "memory")
#define BAR() do { __builtin_amdgcn_s_barrier();                              \
                   __builtin_amdgcn_sched_barrier(0); } while (0)
#define COMPUTE(kidx, BX) do {                                                \
        const char* lb_ = Abuf[(kidx) & 3];                                   \
        _Pragma("unroll")                                                     \
        for (int mt = 0; mt < 2; ++mt) {                                      \
            const char* rbase_ = lb_ + (mt * 16 + fr) * 512;                  \
            _Pragma("unroll")                                                 \
            for (int ks = 0; ks < 4; ++ks) {                                  \
                float4 fa_ = *(const float4*)(rbase_ + ((ks * 8 + ((g * 2 + 0) ^ xr)) << 4)); \
                float4 fb_ = *(const float4*)(rbase_ + ((ks * 8 + ((g * 2 + 1) ^ xr)) << 4)); \
                bf16x8 af_ = cvt8(fa_, fb_);                                  \
                acc[mt][0] = __builtin_amdgcn_mfma_f32_16x16x32_bf16(af_, BX[0][ks], acc[mt][0], 0, 0, 0); \
                acc[mt][1] = __builtin_amdgcn_mfma_f32_16x16x32_bf16(af_, BX[1][ks], acc[mt][1], 0, 0, 0); \
            }                                                                 \
        }                                                                     \
    } while (0)

    // ---- prologue: stage 0,1; B(0) into bank A ----
    STAGE(0);
    STAGE(1);
    LOADB(BfA, 0);

    // ---- main loop: halves k (even) and k+1; stages k+2, k+3 ----
#pragma unroll 1
    for (int k = 0; k < NSTEP - 3; k += 2) {
        LOADB(BfB, k + 1);
        STAGE(k + 2);
        WAITN(16); BAR();
        COMPUTE(k, BfA);

        LOADB(BfA, k + 2);
        STAGE(k + 3);
        WAITN(16); BAR();
        COMPUTE(k + 1, BfB);
    }

    // ---- tail: k = NSTEP-2, NSTEP-1 ----
    LOADB(BfB, NSTEP - 1);
    WAITN(0); BAR();
    COMPUTE(NSTEP - 2, BfA);

    WAITN(0); BAR();
    COMPUTE(NSTEP - 1, BfB);

#undef STAGE
#undef LOADB
#undef WAITN
#undef BAR
#undef COMPUTE

    // ---- fused epilogue: *norm_m + bias, elu ----
    const float* normB = norm + b * NN + m0;
    float* outB = out + ((size_t)b * NN + m0) * HD;
#pragma unroll
    for (int mt = 0; mt < 2; ++mt)
#pragma unroll
        for (int ht = 0; ht < 2; ++ht) {
            const int h  = w * 32 + ht * 16 + fr;
            const float bv = bias[h];
#pragma unroll
            for (int j = 0; j < 4; ++j) {
                const int r = mt * 16 + g * 4 + j;
                float v = acc[mt][ht][j] * normB[r] + bv;
                v = v > 0.f ? v : expm1f(v);
                outB[(size_t)r * HD + h] = v;
            }
        }
}

extern "C" void kernel_launch(void* const* d_in, const int* in_sizes, int n_in,
                              void* d_out, int out_size, void* d_ws, size_t ws_size,
                              hipStream_t stream) {
    (void)in_sizes; (void)n_in; (void)out_size; (void)ws_size;
    const float* x    = (const float*)d_in[0];
    const float* adj  = (const float*)d_in[1];
    const float* W    = (const float*)d_in[2];
    const float* bias = (const float*)d_in[3];
    float* out = (float*)d_out;

    float* norm = (float*)d_ws;                                    // 16384 f32
    __hip_bfloat16* snT = (__hip_bfloat16*)((char*)d_ws + 65536);  // 2x128x8192 bf16 (4 MB)

    k_degree <<<dim3(NB * NN / 4),  dim3(256), 0, stream>>>(adj, norm);
    k_support<<<dim3(NB * NN / 16), dim3(256), 0, stream>>>(x, W, norm, snT);
    k_gemm9  <<<dim3(NN / BM, NB),  dim3(256), 0, stream>>>(adj, snT, norm, bias, out);
}